// Round 9
// baseline (300.365 us; speedup 1.0000x reference)
//
#include <hip/hip_runtime.h>
#include <hip/hip_bf16.h>

#define CHUNK_A 8192      // edges per partition block
#define PB 8              // 256 users per soc bin
#define NBINS_MAX 512     // LDS bound for soc bins (n_user/256 = 391)
#define CAPS_LDS 8800     // soc bin capacity (mean 8192 + ~6.7 sigma)
#define PBM 4             // 16 marked users per bin
#define NBINM_MAX 1024    // marked bins (batch/16)
#define CAPM_LDS 768      // marked bin capacity (mean 512 + ~11 sigma)

__device__ __forceinline__ float bf2f(unsigned short u) {
    return __uint_as_float(((unsigned int)u) << 16);
}
__device__ __forceinline__ unsigned short f2bf(float f) {
    unsigned int x = __float_as_uint(f);
    return (unsigned short)((x + 0x7fffu + ((x >> 16) & 1u)) >> 16);  // RNE
}

// ---------------- kernels ----------------

// f32 -> bf16 for user_emb and item_emb.
__global__ __launch_bounds__(256) void conv_kernel(const float* __restrict__ a,
                                                   unsigned short* __restrict__ oa, long long na,
                                                   const float* __restrict__ b,
                                                   unsigned short* __restrict__ ob, long long nb) {
    long long i4 = ((long long)blockIdx.x * blockDim.x + threadIdx.x) * 4;
    if (i4 < na) {
        float4 f = *(const float4*)&a[i4];
        ushort4 o = { f2bf(f.x), f2bf(f.y), f2bf(f.z), f2bf(f.w) };
        *(ushort4*)&oa[i4] = o;
    }
    if (i4 < nb) {
        float4 f = *(const float4*)&b[i4];
        ushort4 o = { f2bf(f.x), f2bf(f.y), f2bf(f.z), f2bf(f.w) };
        *(ushort4*)&ob[i4] = o;
    }
}

// Dedup-mark users (mark[u]=compact+1) and init all bin cursors.
__global__ __launch_bounds__(256) void mark_init_kernel(const int* __restrict__ ids,
                                                        int* __restrict__ mark,
                                                        int* __restrict__ n_marked, int n,
                                                        int* __restrict__ curS, int nbinS, int capS,
                                                        int* __restrict__ curMS,
                                                        int* __restrict__ curMI, int capM) {
    int i = blockIdx.x * blockDim.x + threadIdx.x;
    if (i < nbinS) curS[i] = i * capS;
    if (i < NBINM_MAX) { curMS[i] = i * capM; curMI[i] = i * capM; }
    if (i < n) {
        int u = ids[i];
        if (atomicCAS(&mark[u], 0, -1) == 0) {
            int m = atomicAdd(n_marked, 1);
            mark[u] = m + 1;
        }
    }
}

// Phase A (soc): partition soc edges into 256-user bins -> bufS; ALSO route edges
// whose row is marked into 16-marked-user bins -> bufMS (for the layer-2 pass).
__global__ __launch_bounds__(512) void partA_soc(const int* __restrict__ rows,
                                                 const int* __restrict__ cols,
                                                 const float* __restrict__ vals,
                                                 const int* __restrict__ mark,
                                                 int* __restrict__ curS,
                                                 int2* __restrict__ bufS,
                                                 int* __restrict__ curMS,
                                                 int2* __restrict__ bufMS,
                                                 int E, int nbinS, int capS, int capM) {
    __shared__ int hist[NBINS_MAX], gbase[NBINS_MAX], lcur[NBINS_MAX];
    __shared__ int histM[NBINM_MAX], gbaseM[NBINM_MAX], lcurM[NBINM_MAX];
    int tid = threadIdx.x;
    int base = blockIdx.x * CHUNK_A;
    int lim = min(base + CHUNK_A, E);
    for (int b = tid; b < nbinS; b += 512) hist[b] = 0;
    for (int b = tid; b < NBINM_MAX; b += 512) histM[b] = 0;
    __syncthreads();
    for (int i = base + tid; i < lim; i += 512) {
        int r = rows[i];
        atomicAdd(&hist[r >> PB], 1);
        int m = mark[r];
        if (m > 0) atomicAdd(&histM[(m - 1) >> PBM], 1);
    }
    __syncthreads();
    for (int b = tid; b < nbinS; b += 512) {
        int h = hist[b]; gbase[b] = h ? atomicAdd(&curS[b], h) : 0; lcur[b] = 0;
    }
    for (int b = tid; b < NBINM_MAX; b += 512) {
        int h = histM[b]; gbaseM[b] = h ? atomicAdd(&curMS[b], h) : 0; lcurM[b] = 0;
    }
    __syncthreads();
    for (int i = base + tid; i < lim; i += 512) {
        int r = rows[i], c = cols[i];
        int vb = __float_as_int(vals[i]);
        int b = r >> PB;
        int off = atomicAdd(&lcur[b], 1);
        long long dst = (long long)gbase[b] + off;
        if (dst < (long long)(b + 1) * capS) bufS[dst] = make_int2(((r & 255) << 17) | c, vb);
        int m = mark[r];
        if (m > 0) {
            m -= 1;
            int bm = m >> PBM;
            int offm = atomicAdd(&lcurM[bm], 1);
            long long dm = (long long)gbaseM[bm] + offm;
            if (dm < (long long)(bm + 1) * capM) bufMS[dm] = make_int2(((m & 15) << 17) | c, vb);
        }
    }
}

// Phase A (info): partition info edges with marked rows into 16-user bins -> bufMI.
__global__ __launch_bounds__(512) void partA_info(const int* __restrict__ ir,
                                                  const int* __restrict__ ic,
                                                  const float* __restrict__ iv, int Ei,
                                                  const int* __restrict__ mark,
                                                  int* __restrict__ cur,
                                                  int2* __restrict__ buf, int capm) {
    __shared__ int hist[NBINM_MAX], gbase[NBINM_MAX], lcur[NBINM_MAX];
    int tid = threadIdx.x;
    int base = blockIdx.x * CHUNK_A;
    int lim = min(base + CHUNK_A, Ei);
    for (int b = tid; b < NBINM_MAX; b += 512) hist[b] = 0;
    __syncthreads();
    for (int i = base + tid; i < lim; i += 512) {
        int m = mark[ir[i]];
        if (m > 0) atomicAdd(&hist[(m - 1) >> PBM], 1);
    }
    __syncthreads();
    for (int b = tid; b < NBINM_MAX; b += 512) {
        int h = hist[b]; gbase[b] = h ? atomicAdd(&cur[b], h) : 0; lcur[b] = 0;
    }
    __syncthreads();
    for (int i = base + tid; i < lim; i += 512) {
        int m = mark[ir[i]];
        if (m <= 0) continue;
        m -= 1;
        int b = m >> PBM;
        int off = atomicAdd(&lcur[b], 1);
        long long dst = (long long)gbase[b] + off;
        if (dst < (long long)(b + 1) * capm)
            buf[dst] = make_int2(((m & 15) << 17) | ic[i], __float_as_int(iv[i]));
    }
}

// Phase B (h1): per 256-user soc bin, LDS counting-sort by local row, then
// register-accum gather. h1[r] = (sum val*ub[col])/(sum val+eps) + ub[r], bf16.
__global__ __launch_bounds__(512) void partB_h1(const int* __restrict__ curS,
                                                const int2* __restrict__ bufS,
                                                const unsigned short* __restrict__ ub,
                                                unsigned short* __restrict__ hb,
                                                int n_user, int capS) {
    int bin = blockIdx.x;
    int rows0 = bin << PB;
    int nrows = min(256, n_user - rows0);
    __shared__ int2 sorted[CAPS_LDS];
    __shared__ int j0[257], cur[256], wsum[4];
    int tid = threadIdx.x;
    if (tid < 256) cur[tid] = 0;
    __syncthreads();
    long long gstart = (long long)bin * capS;
    long long gend = curS[bin];
    if (gend > gstart + capS) gend = gstart + capS;
    int cnt = (int)(gend - gstart);
    for (int i = tid; i < cnt; i += 512) atomicAdd(&cur[bufS[gstart + i].x >> 17], 1);
    __syncthreads();
    int lane = tid & 63, wid = tid >> 6;
    int x = 0, v = 0;
    if (tid < 256) {
        x = cur[tid]; v = x;
        #pragma unroll
        for (int d = 1; d < 64; d <<= 1) { int y = __shfl_up(v, d); if (lane >= d) v += y; }
        if (lane == 63) wsum[wid] = v;
    }
    __syncthreads();
    if (tid == 0) {
        int s = 0;
        #pragma unroll
        for (int k = 0; k < 4; ++k) { int t = wsum[k]; wsum[k] = s; s += t; }
        j0[256] = s;
    }
    __syncthreads();
    if (tid < 256) { int excl = wsum[wid] + v - x; j0[tid] = excl; cur[tid] = excl; }
    __syncthreads();
    for (int i = tid; i < cnt; i += 512) {
        int2 e = bufS[gstart + i];
        int rl = e.x >> 17;
        int p = atomicAdd(&cur[rl], 1);
        sorted[p] = make_int2(e.x & 0x1FFFF, e.y);
    }
    __syncthreads();
    int sub = lane >> 4, d4 = (lane & 15) << 2;
    for (int r = wid; r < nrows; r += 8) {
        int a = j0[r], b2 = j0[r + 1];
        float4 acc = make_float4(0.f, 0.f, 0.f, 0.f);
        float degs = 0.f;
        for (int j = a + sub; j < b2; j += 4) {
            int2 e = sorted[j];
            float vv = __int_as_float(e.y);
            ushort4 q = *(const ushort4*)&ub[(long long)e.x * 64 + d4];
            acc.x += vv * bf2f(q.x); acc.y += vv * bf2f(q.y);
            acc.z += vv * bf2f(q.z); acc.w += vv * bf2f(q.w);
            degs += vv;
        }
        #pragma unroll
        for (int m = 16; m < 64; m <<= 1) {
            acc.x += __shfl_xor(acc.x, m); acc.y += __shfl_xor(acc.y, m);
            acc.z += __shfl_xor(acc.z, m); acc.w += __shfl_xor(acc.w, m);
            degs  += __shfl_xor(degs, m);
        }
        if (sub == 0) {
            float inv = 1.0f / (degs + 1e-8f);
            ushort4 qe = *(const ushort4*)&ub[(long long)(rows0 + r) * 64 + d4];
            ushort4 o = { f2bf(fmaf(acc.x, inv, bf2f(qe.x))),
                          f2bf(fmaf(acc.y, inv, bf2f(qe.y))),
                          f2bf(fmaf(acc.z, inv, bf2f(qe.z))),
                          f2bf(fmaf(acc.w, inv, bf2f(qe.w))) };
            *(ushort4*)&hb[(long long)(rows0 + r) * 64 + d4] = o;
        }
    }
}

// Phase B (accF): per 16-marked-user bin, sort bufMS (gather h1) and bufMI
// (gather item_emb); accF[m] = sS/degS + sI/degI, f32 compact.
__global__ __launch_bounds__(256) void partB_accM(const int* __restrict__ n_marked,
                                                  const int* __restrict__ curMS,
                                                  const int2* __restrict__ bufMS,
                                                  const unsigned short* __restrict__ hb,
                                                  const int* __restrict__ curMI,
                                                  const int2* __restrict__ bufMI,
                                                  const unsigned short* __restrict__ ib,
                                                  float* __restrict__ accF, int capM) {
    int bin = blockIdx.x;
    int nm = *n_marked;
    int rows0 = bin << PBM;
    if (rows0 >= nm) return;
    int nrows = min(16, nm - rows0);
    __shared__ int2 sS[CAPM_LDS], sI[CAPM_LDS];
    __shared__ int j0S[17], j0I[17], cS[16], cI[16];
    int tid = threadIdx.x;
    if (tid < 16) { cS[tid] = 0; cI[tid] = 0; }
    __syncthreads();
    long long gsS = (long long)bin * capM;
    long long geS = curMS[bin];
    if (geS > gsS + capM) geS = gsS + capM;
    int cntS = (int)(geS - gsS);
    long long gsI = (long long)bin * capM;
    long long geI = curMI[bin];
    if (geI > gsI + capM) geI = gsI + capM;
    int cntI = (int)(geI - gsI);
    for (int i = tid; i < cntS; i += 256) atomicAdd(&cS[bufMS[gsS + i].x >> 17], 1);
    for (int i = tid; i < cntI; i += 256) atomicAdd(&cI[bufMI[gsI + i].x >> 17], 1);
    __syncthreads();
    int lane = tid & 63, wid = tid >> 6;
    if (wid == 0 && lane < 16) {
        int x = cS[lane], v = x;
        #pragma unroll
        for (int d = 1; d < 16; d <<= 1) { int y = __shfl_up(v, d); if (lane >= d) v += y; }
        j0S[lane] = v - x; cS[lane] = v - x;
        if (lane == 15) j0S[16] = v;
    } else if (wid == 1 && lane < 16) {
        int x = cI[lane], v = x;
        #pragma unroll
        for (int d = 1; d < 16; d <<= 1) { int y = __shfl_up(v, d); if (lane >= d) v += y; }
        j0I[lane] = v - x; cI[lane] = v - x;
        if (lane == 15) j0I[16] = v;
    }
    __syncthreads();
    for (int i = tid; i < cntS; i += 256) {
        int2 e = bufMS[gsS + i];
        int p = atomicAdd(&cS[e.x >> 17], 1);
        sS[p] = make_int2(e.x & 0x1FFFF, e.y);
    }
    for (int i = tid; i < cntI; i += 256) {
        int2 e = bufMI[gsI + i];
        int p = atomicAdd(&cI[e.x >> 17], 1);
        sI[p] = make_int2(e.x & 0x1FFFF, e.y);
    }
    __syncthreads();
    int sub = lane >> 4, d4 = (lane & 15) << 2;
    for (int r = wid; r < nrows; r += 4) {
        float4 aS = make_float4(0.f, 0.f, 0.f, 0.f);
        float dS = 0.f;
        int a = j0S[r], b2 = j0S[r + 1];
        for (int j = a + sub; j < b2; j += 4) {
            int2 e = sS[j];
            float vv = __int_as_float(e.y);
            ushort4 q = *(const ushort4*)&hb[(long long)e.x * 64 + d4];
            aS.x += vv * bf2f(q.x); aS.y += vv * bf2f(q.y);
            aS.z += vv * bf2f(q.z); aS.w += vv * bf2f(q.w);
            dS += vv;
        }
        float4 aI = make_float4(0.f, 0.f, 0.f, 0.f);
        float dI = 0.f;
        a = j0I[r]; b2 = j0I[r + 1];
        for (int j = a + sub; j < b2; j += 4) {
            int2 e = sI[j];
            float vv = __int_as_float(e.y);
            ushort4 q = *(const ushort4*)&ib[(long long)e.x * 64 + d4];
            aI.x += vv * bf2f(q.x); aI.y += vv * bf2f(q.y);
            aI.z += vv * bf2f(q.z); aI.w += vv * bf2f(q.w);
            dI += vv;
        }
        #pragma unroll
        for (int m = 16; m < 64; m <<= 1) {
            aS.x += __shfl_xor(aS.x, m); aS.y += __shfl_xor(aS.y, m);
            aS.z += __shfl_xor(aS.z, m); aS.w += __shfl_xor(aS.w, m);
            dS   += __shfl_xor(dS, m);
            aI.x += __shfl_xor(aI.x, m); aI.y += __shfl_xor(aI.y, m);
            aI.z += __shfl_xor(aI.z, m); aI.w += __shfl_xor(aI.w, m);
            dI   += __shfl_xor(dI, m);
        }
        if (sub == 0) {
            float invS = 1.0f / (dS + 1e-8f);
            float invI = 1.0f / (dI + 1e-8f);
            float4 o = make_float4(aS.x * invS + aI.x * invI,
                                   aS.y * invS + aI.y * invI,
                                   aS.z * invS + aI.z * invI,
                                   aS.w * invS + aI.w * invI);
            *(float4*)&accF[(long long)(rows0 + r) * 64 + d4] = o;
        }
    }
}

// out[i] = sigmoid( dot(2*h1[uid] + accF[mark[uid]-1], 2*item_emb[iid]) )
__global__ __launch_bounds__(256) void dot_kernel(const unsigned short* __restrict__ hb,
                                                  const float* __restrict__ accF,
                                                  const unsigned short* __restrict__ ib,
                                                  const int* __restrict__ mark,
                                                  const int* __restrict__ uids,
                                                  const int* __restrict__ iids,
                                                  float* __restrict__ out, int batch) {
    int w = (int)((blockIdx.x * (long long)blockDim.x + threadIdx.x) >> 6);
    int lane = threadIdx.x & 63;
    if (w >= batch) return;
    int u = uids[w], it = iids[w];
    long long m = (long long)(mark[u] - 1);
    float uv = 2.0f * bf2f(hb[(long long)u * 64 + lane]) + accF[m * 64 + lane];
    float vv = 2.0f * bf2f(ib[(long long)it * 64 + lane]);
    float p = uv * vv;
    #pragma unroll
    for (int off = 32; off; off >>= 1) p += __shfl_xor(p, off);
    if (lane == 0) out[w] = 1.0f / (1.0f + __expf(-p));
}

// ---------------- launch ----------------

extern "C" void kernel_launch(void* const* d_in, const int* in_sizes, int n_in,
                              void* d_out, int out_size, void* d_ws, size_t ws_size,
                              hipStream_t stream) {
    const float* user_emb  = (const float*)d_in[0];
    const float* item_emb  = (const float*)d_in[1];
    const int*   soc_rows  = (const int*)d_in[2];
    const int*   soc_cols  = (const int*)d_in[3];
    const float* soc_vals  = (const float*)d_in[4];
    const int*   info_rows = (const int*)d_in[5];
    const int*   info_cols = (const int*)d_in[6];
    const float* info_vals = (const float*)d_in[7];
    const int*   user_ids  = (const int*)d_in[8];
    const int*   item_ids  = (const int*)d_in[9];
    float*       out       = (float*)d_out;

    const int n_user = in_sizes[0] / 64;
    const int n_item = in_sizes[1] / 64;
    const int E_soc  = in_sizes[2];
    const int E_info = in_sizes[5];
    const int batch  = in_sizes[8];

    const int nbinS = (n_user + 255) >> PB;
    int capS = (int)((long long)E_soc * 256 / n_user);
    capS = capS + capS / 16 + 96;
    if (capS > CAPS_LDS) capS = CAPS_LDS;
    const int Emax = max(E_soc, E_info);
    int capM = (int)((long long)Emax * 16 / n_user);
    capM = capM + capM / 4 + 64;
    if (capM > CAPM_LDS) capM = CAPM_LDS;

    // ---- workspace layout ----
    char* p = (char*)d_ws;
    auto alloc = [&](size_t bytes) { char* q = p; p += (bytes + 255) & ~size_t(255); return q; };
    int* mark     = (int*)alloc(sizeof(int) * n_user);
    int* n_marked = (int*)alloc(sizeof(int) * 64);
    size_t zero_bytes = (size_t)(p - (char*)d_ws);
    int*  curSoc = (int*)alloc(sizeof(int) * nbinS);
    int*  curMS  = (int*)alloc(sizeof(int) * NBINM_MAX);
    int*  curMI  = (int*)alloc(sizeof(int) * NBINM_MAX);
    int2* bufSoc = (int2*)alloc(sizeof(int2) * (size_t)nbinS * capS);       // ~27.5 MB
    int2* bufMS  = (int2*)alloc(sizeof(int2) * (size_t)NBINM_MAX * capM);   // ~6 MB
    int2* bufMI  = (int2*)alloc(sizeof(int2) * (size_t)NBINM_MAX * capM);   // ~6 MB
    unsigned short* ub = (unsigned short*)alloc(sizeof(short) * (size_t)n_user * 64);
    unsigned short* ib = (unsigned short*)alloc(sizeof(short) * (size_t)n_item * 64);
    unsigned short* hb = (unsigned short*)alloc(sizeof(short) * (size_t)n_user * 64);
    float* accF        = (float*)alloc(sizeof(float) * (size_t)batch * 64);
    (void)ws_size;

    hipMemsetAsync(d_ws, 0, zero_bytes, stream);

    const int B = 256;
    long long na = (long long)n_user * 64, nbm = (long long)n_item * 64;
    long long c4 = (na > nbm ? na : nbm) / 4;
    conv_kernel<<<(int)((c4 + B - 1) / B), B, 0, stream>>>(user_emb, ub, na, item_emb, ib, nbm);

    mark_init_kernel<<<(batch + B - 1) / B, B, 0, stream>>>(user_ids, mark, n_marked, batch,
                                                            curSoc, nbinS, capS,
                                                            curMS, curMI, capM);

    int gA = (E_soc + CHUNK_A - 1) / CHUNK_A;
    partA_soc<<<gA, 512, 0, stream>>>(soc_rows, soc_cols, soc_vals, mark,
                                      curSoc, bufSoc, curMS, bufMS,
                                      E_soc, nbinS, capS, capM);

    int gAi = (E_info + CHUNK_A - 1) / CHUNK_A;
    partA_info<<<gAi, 512, 0, stream>>>(info_rows, info_cols, info_vals, E_info,
                                        mark, curMI, bufMI, capM);

    partB_h1<<<nbinS, 512, 0, stream>>>(curSoc, bufSoc, ub, hb, n_user, capS);

    int gBm = (batch + 15) >> PBM;
    partB_accM<<<gBm, B, 0, stream>>>(n_marked, curMS, bufMS, hb, curMI, bufMI, ib, accF, capM);

    long long t2 = (long long)batch * 64;
    dot_kernel<<<(int)((t2 + B - 1) / B), B, 0, stream>>>(hb, accF, ib, mark,
                                                          user_ids, item_ids, out, batch);
}

// Round 10
// 276.951 us; speedup vs baseline: 1.0845x; 1.0845x over previous
//
#include <hip/hip_runtime.h>
#include <hip/hip_bf16.h>

#define CHUNK_A 4096      // edges per partition block
#define PB 8              // 256 users per soc bin
#define NBINS_MAX 512     // LDS bound for soc bins (n_user/256 = 391)
#define CAPS 8800         // soc bin capacity (mean 8192 + ~6.7 sigma)
#define PBM 4             // 16 marked users per bin
#define NBINM_MAX 1024    // marked bins (batch/16)
#define CAPM_LDS 768      // marked-info bin capacity (mean 512 + ~11 sigma)

__device__ __forceinline__ float bf2f(unsigned short u) {
    return __uint_as_float(((unsigned int)u) << 16);
}
__device__ __forceinline__ unsigned short f2bf(float f) {
    unsigned int x = __float_as_uint(f);
    return (unsigned short)((x + 0x7fffu + ((x >> 16) & 1u)) >> 16);  // RNE
}
__device__ __forceinline__ void unpk(unsigned int u, float& lo, float& hi) {
    lo = __uint_as_float(u << 16);
    hi = __uint_as_float(u & 0xffff0000u);
}
__device__ __forceinline__ unsigned int pack2(float lo, float hi) {
    return (unsigned int)f2bf(lo) | ((unsigned int)f2bf(hi) << 16);
}

// ---------------- kernels ----------------

// f32 -> bf16 for user_emb and item_emb.
__global__ __launch_bounds__(256) void conv_kernel(const float* __restrict__ a,
                                                   unsigned short* __restrict__ oa, long long na,
                                                   const float* __restrict__ b,
                                                   unsigned short* __restrict__ ob, long long nb) {
    long long i4 = ((long long)blockIdx.x * blockDim.x + threadIdx.x) * 4;
    if (i4 < na) {
        float4 f = *(const float4*)&a[i4];
        ushort4 o = { f2bf(f.x), f2bf(f.y), f2bf(f.z), f2bf(f.w) };
        *(ushort4*)&oa[i4] = o;
    }
    if (i4 < nb) {
        float4 f = *(const float4*)&b[i4];
        ushort4 o = { f2bf(f.x), f2bf(f.y), f2bf(f.z), f2bf(f.w) };
        *(ushort4*)&ob[i4] = o;
    }
}

// Dedup-mark users (mark[u]=compact+1, mlist) and init bin cursors.
__global__ __launch_bounds__(256) void mark_init_kernel(const int* __restrict__ ids,
                                                        int* __restrict__ mark,
                                                        int* __restrict__ mlist,
                                                        int* __restrict__ n_marked, int n,
                                                        int* __restrict__ curS, int nbinS, int capS,
                                                        int* __restrict__ curMI, int capM) {
    int i = blockIdx.x * blockDim.x + threadIdx.x;
    if (i < nbinS) curS[i] = i * capS;
    if (i < NBINM_MAX) curMI[i] = i * capM;
    if (i < n) {
        int u = ids[i];
        if (atomicCAS(&mark[u], 0, -1) == 0) {
            int m = atomicAdd(n_marked, 1);
            mlist[m] = u;
            mark[u] = m + 1;
        }
    }
}

// Phase A (soc): partition soc edges into 256-user bins (coarse radix pass).
__global__ __launch_bounds__(512) void partA_soc(const int* __restrict__ rows,
                                                 const int* __restrict__ cols,
                                                 const float* __restrict__ vals,
                                                 int* __restrict__ curS,
                                                 int2* __restrict__ bufS,
                                                 int E, int nbinS, int capS) {
    __shared__ int hist[NBINS_MAX], gbase[NBINS_MAX], lcur[NBINS_MAX];
    int tid = threadIdx.x;
    int base = blockIdx.x * CHUNK_A;
    int lim = min(base + CHUNK_A, E);
    for (int b = tid; b < nbinS; b += 512) hist[b] = 0;
    __syncthreads();
    for (int i = base + tid; i < lim; i += 512) atomicAdd(&hist[rows[i] >> PB], 1);
    __syncthreads();
    for (int b = tid; b < nbinS; b += 512) {
        int h = hist[b]; gbase[b] = h ? atomicAdd(&curS[b], h) : 0; lcur[b] = 0;
    }
    __syncthreads();
    for (int i = base + tid; i < lim; i += 512) {
        int r = rows[i];
        int b = r >> PB;
        int off = atomicAdd(&lcur[b], 1);
        long long dst = (long long)gbase[b] + off;
        if (dst < (long long)(b + 1) * capS)
            bufS[dst] = make_int2(((r & 255) << 17) | cols[i], __float_as_int(vals[i]));
    }
}

// Phase A (info): partition info edges with marked rows into 16-marked-user bins.
__global__ __launch_bounds__(512) void partA_info(const int* __restrict__ ir,
                                                  const int* __restrict__ ic,
                                                  const float* __restrict__ iv, int Ei,
                                                  const int* __restrict__ mark,
                                                  int* __restrict__ cur,
                                                  int2* __restrict__ buf, int capm) {
    __shared__ int hist[NBINM_MAX], gbase[NBINM_MAX], lcur[NBINM_MAX];
    int tid = threadIdx.x;
    int base = blockIdx.x * CHUNK_A;
    int lim = min(base + CHUNK_A, Ei);
    for (int b = tid; b < NBINM_MAX; b += 512) hist[b] = 0;
    __syncthreads();
    for (int i = base + tid; i < lim; i += 512) {
        int m = mark[ir[i]];
        if (m > 0) atomicAdd(&hist[(m - 1) >> PBM], 1);
    }
    __syncthreads();
    for (int b = tid; b < NBINM_MAX; b += 512) {
        int h = hist[b]; gbase[b] = h ? atomicAdd(&cur[b], h) : 0; lcur[b] = 0;
    }
    __syncthreads();
    for (int i = base + tid; i < lim; i += 512) {
        int m = mark[ir[i]];
        if (m <= 0) continue;
        m -= 1;
        int b = m >> PBM;
        int off = atomicAdd(&lcur[b], 1);
        long long dst = (long long)gbase[b] + off;
        if (dst < (long long)(b + 1) * capm)
            buf[dst] = make_int2(((m & 15) << 17) | ic[i], __float_as_int(iv[i]));
    }
}

// Phase B sort: per soc bin, LDS hist+scan of 256 local rows, then write the
// fully row-sorted CSR (col,val) + per-row [start,end) to rowptr2. Tiny LDS.
__global__ __launch_bounds__(512) void partB_sort(const int* __restrict__ curS,
                                                  const int2* __restrict__ bufS,
                                                  int2* __restrict__ csr,
                                                  int2* __restrict__ rowptr2,
                                                  int n_user, int capS) {
    int bin = blockIdx.x;
    int rows0 = bin << PB;
    int nrows = min(256, n_user - rows0);
    __shared__ int cur[256], wsum[4];
    int tid = threadIdx.x;
    if (tid < 256) cur[tid] = 0;
    __syncthreads();
    int gstart = bin * capS;
    int gend = curS[bin];
    if (gend > gstart + capS) gend = gstart + capS;
    int cnt = gend - gstart;
    for (int i = tid; i < cnt; i += 512) atomicAdd(&cur[bufS[gstart + i].x >> 17], 1);
    __syncthreads();
    int lane = tid & 63, wid = tid >> 6;
    int x = 0, v = 0;
    if (tid < 256) {
        x = cur[tid]; v = x;
        #pragma unroll
        for (int d = 1; d < 64; d <<= 1) { int y = __shfl_up(v, d); if (lane >= d) v += y; }
        if (lane == 63) wsum[wid] = v;
    }
    __syncthreads();
    if (tid == 0) {
        int s = 0;
        #pragma unroll
        for (int k = 0; k < 4; ++k) { int t = wsum[k]; wsum[k] = s; s += t; }
    }
    __syncthreads();
    if (tid < 256) {
        int excl = wsum[wid] + v - x;
        if (tid < nrows) rowptr2[rows0 + tid] = make_int2(gstart + excl, gstart + excl + x);
        cur[tid] = excl;
    }
    __syncthreads();
    for (int i = tid; i < cnt; i += 512) {
        int2 e = bufS[gstart + i];
        int rl = e.x >> 17;
        int p = atomicAdd(&cur[rl], 1);
        csr[gstart + p] = make_int2(e.x & 0x1FFFF, e.y);
    }
}

// gather1: one wave per user row; 8 edge slots x 8 lanes x ushort8 (int4) loads.
// h1[r] = (sum val*ub[col])/(sum val+eps) + ub[r], bf16 out.
__global__ __launch_bounds__(256) void gather1_kernel(const int2* __restrict__ rowptr2,
                                                      const int2* __restrict__ csr,
                                                      const unsigned short* __restrict__ ub,
                                                      unsigned short* __restrict__ hb,
                                                      int n_user) {
    int w = (int)((blockIdx.x * (long long)blockDim.x + threadIdx.x) >> 6);
    if (w >= n_user) return;
    int lane = threadIdx.x & 63;
    int sub = lane >> 3;
    int d8 = (lane & 7) << 3;
    int2 seg = rowptr2[w];
    float a0 = 0, a1 = 0, a2 = 0, a3 = 0, a4 = 0, a5 = 0, a6 = 0, a7 = 0, degs = 0;
    for (int j = seg.x + sub; j < seg.y; j += 8) {
        int2 e = csr[j];
        float vv = __int_as_float(e.y);
        int4 q = *(const int4*)&ub[(long long)e.x * 64 + d8];
        float f0, f1, f2, f3, f4, f5, f6, f7;
        unpk(q.x, f0, f1); unpk(q.y, f2, f3); unpk(q.z, f4, f5); unpk(q.w, f6, f7);
        a0 += vv * f0; a1 += vv * f1; a2 += vv * f2; a3 += vv * f3;
        a4 += vv * f4; a5 += vv * f5; a6 += vv * f6; a7 += vv * f7;
        degs += vv;
    }
    #pragma unroll
    for (int m = 8; m < 64; m <<= 1) {
        a0 += __shfl_xor(a0, m); a1 += __shfl_xor(a1, m);
        a2 += __shfl_xor(a2, m); a3 += __shfl_xor(a3, m);
        a4 += __shfl_xor(a4, m); a5 += __shfl_xor(a5, m);
        a6 += __shfl_xor(a6, m); a7 += __shfl_xor(a7, m);
        degs += __shfl_xor(degs, m);
    }
    if (sub == 0) {
        float inv = 1.0f / (degs + 1e-8f);
        int4 qe = *(const int4*)&ub[(long long)w * 64 + d8];
        float g0, g1, g2, g3, g4, g5, g6, g7;
        unpk(qe.x, g0, g1); unpk(qe.y, g2, g3); unpk(qe.z, g4, g5); unpk(qe.w, g6, g7);
        int4 o;
        o.x = (int)pack2(fmaf(a0, inv, g0), fmaf(a1, inv, g1));
        o.y = (int)pack2(fmaf(a2, inv, g2), fmaf(a3, inv, g3));
        o.z = (int)pack2(fmaf(a4, inv, g4), fmaf(a5, inv, g5));
        o.w = (int)pack2(fmaf(a6, inv, g6), fmaf(a7, inv, g7));
        *(int4*)&hb[(long long)w * 64 + d8] = o;
    }
}

// accS: one wave per marked row; gather h1 rows via the soc CSR.
// accS[m] = (sum val*hb[col])/(sum val+eps), f32 compact.
__global__ __launch_bounds__(256) void accS_kernel(const int* __restrict__ mlist,
                                                   const int* __restrict__ n_marked,
                                                   const int2* __restrict__ rowptr2,
                                                   const int2* __restrict__ csr,
                                                   const unsigned short* __restrict__ hb,
                                                   float* __restrict__ accS) {
    int w = (int)((blockIdx.x * (long long)blockDim.x + threadIdx.x) >> 6);
    if (w >= *n_marked) return;
    int lane = threadIdx.x & 63;
    int sub = lane >> 3;
    int d8 = (lane & 7) << 3;
    int r = mlist[w];
    int2 seg = rowptr2[r];
    float a0 = 0, a1 = 0, a2 = 0, a3 = 0, a4 = 0, a5 = 0, a6 = 0, a7 = 0, degs = 0;
    for (int j = seg.x + sub; j < seg.y; j += 8) {
        int2 e = csr[j];
        float vv = __int_as_float(e.y);
        int4 q = *(const int4*)&hb[(long long)e.x * 64 + d8];
        float f0, f1, f2, f3, f4, f5, f6, f7;
        unpk(q.x, f0, f1); unpk(q.y, f2, f3); unpk(q.z, f4, f5); unpk(q.w, f6, f7);
        a0 += vv * f0; a1 += vv * f1; a2 += vv * f2; a3 += vv * f3;
        a4 += vv * f4; a5 += vv * f5; a6 += vv * f6; a7 += vv * f7;
        degs += vv;
    }
    #pragma unroll
    for (int m = 8; m < 64; m <<= 1) {
        a0 += __shfl_xor(a0, m); a1 += __shfl_xor(a1, m);
        a2 += __shfl_xor(a2, m); a3 += __shfl_xor(a3, m);
        a4 += __shfl_xor(a4, m); a5 += __shfl_xor(a5, m);
        a6 += __shfl_xor(a6, m); a7 += __shfl_xor(a7, m);
        degs += __shfl_xor(degs, m);
    }
    if (sub == 0) {
        float inv = 1.0f / (degs + 1e-8f);
        long long base = (long long)w * 64 + d8;
        float4 o0 = { a0 * inv, a1 * inv, a2 * inv, a3 * inv };
        float4 o1 = { a4 * inv, a5 * inv, a6 * inv, a7 * inv };
        *(float4*)&accS[base] = o0;
        *(float4*)&accS[base + 4] = o1;
    }
}

// accI: per 16-marked-user bin, LDS sort bufMI, gather item_emb.
// accI[m] = (sum val*ib[col])/(sum val+eps), f32 compact.
__global__ __launch_bounds__(256) void partB_accI(const int* __restrict__ n_marked,
                                                  const int* __restrict__ curMI,
                                                  const int2* __restrict__ bufMI,
                                                  const unsigned short* __restrict__ ib,
                                                  float* __restrict__ accI, int capM) {
    int bin = blockIdx.x;
    int nm = *n_marked;
    int rows0 = bin << PBM;
    if (rows0 >= nm) return;
    int nrows = min(16, nm - rows0);
    __shared__ int2 sI[CAPM_LDS];
    __shared__ int j0[17], cI[16];
    int tid = threadIdx.x;
    if (tid < 16) cI[tid] = 0;
    __syncthreads();
    long long gs = (long long)bin * capM;
    long long ge = curMI[bin];
    if (ge > gs + capM) ge = gs + capM;
    int cnt = (int)(ge - gs);
    for (int i = tid; i < cnt; i += 256) atomicAdd(&cI[bufMI[gs + i].x >> 17], 1);
    __syncthreads();
    int lane = tid & 63, wid = tid >> 6;
    if (wid == 0 && lane < 16) {
        int x = cI[lane], v = x;
        #pragma unroll
        for (int d = 1; d < 16; d <<= 1) { int y = __shfl_up(v, d); if (lane >= d) v += y; }
        j0[lane] = v - x; cI[lane] = v - x;
        if (lane == 15) j0[16] = v;
    }
    __syncthreads();
    for (int i = tid; i < cnt; i += 256) {
        int2 e = bufMI[gs + i];
        int p = atomicAdd(&cI[e.x >> 17], 1);
        sI[p] = make_int2(e.x & 0x1FFFF, e.y);
    }
    __syncthreads();
    int sub = lane >> 4, d4 = (lane & 15) << 2;
    for (int r = wid; r < nrows; r += 4) {
        int a = j0[r], b2 = j0[r + 1];
        float4 acc = make_float4(0.f, 0.f, 0.f, 0.f);
        float degs = 0.f;
        for (int j = a + sub; j < b2; j += 4) {
            int2 e = sI[j];
            float vv = __int_as_float(e.y);
            ushort4 q = *(const ushort4*)&ib[(long long)e.x * 64 + d4];
            acc.x += vv * bf2f(q.x); acc.y += vv * bf2f(q.y);
            acc.z += vv * bf2f(q.z); acc.w += vv * bf2f(q.w);
            degs += vv;
        }
        #pragma unroll
        for (int m = 16; m < 64; m <<= 1) {
            acc.x += __shfl_xor(acc.x, m); acc.y += __shfl_xor(acc.y, m);
            acc.z += __shfl_xor(acc.z, m); acc.w += __shfl_xor(acc.w, m);
            degs  += __shfl_xor(degs, m);
        }
        if (sub == 0) {
            float inv = 1.0f / (degs + 1e-8f);
            float4 o = make_float4(acc.x * inv, acc.y * inv, acc.z * inv, acc.w * inv);
            *(float4*)&accI[(long long)(rows0 + r) * 64 + d4] = o;
        }
    }
}

// out[i] = sigmoid( dot(2*h1[uid] + accS[m] + accI[m], 2*item_emb[iid]) )
__global__ __launch_bounds__(256) void dot_kernel(const unsigned short* __restrict__ hb,
                                                  const float* __restrict__ accS,
                                                  const float* __restrict__ accI,
                                                  const unsigned short* __restrict__ ib,
                                                  const int* __restrict__ mark,
                                                  const int* __restrict__ uids,
                                                  const int* __restrict__ iids,
                                                  float* __restrict__ out, int batch) {
    int w = (int)((blockIdx.x * (long long)blockDim.x + threadIdx.x) >> 6);
    int lane = threadIdx.x & 63;
    if (w >= batch) return;
    int u = uids[w], it = iids[w];
    long long m = (long long)(mark[u] - 1);
    float uv = 2.0f * bf2f(hb[(long long)u * 64 + lane]) + accS[m * 64 + lane] + accI[m * 64 + lane];
    float vv = 2.0f * bf2f(ib[(long long)it * 64 + lane]);
    float p = uv * vv;
    #pragma unroll
    for (int off = 32; off; off >>= 1) p += __shfl_xor(p, off);
    if (lane == 0) out[w] = 1.0f / (1.0f + __expf(-p));
}

// ---------------- launch ----------------

extern "C" void kernel_launch(void* const* d_in, const int* in_sizes, int n_in,
                              void* d_out, int out_size, void* d_ws, size_t ws_size,
                              hipStream_t stream) {
    const float* user_emb  = (const float*)d_in[0];
    const float* item_emb  = (const float*)d_in[1];
    const int*   soc_rows  = (const int*)d_in[2];
    const int*   soc_cols  = (const int*)d_in[3];
    const float* soc_vals  = (const float*)d_in[4];
    const int*   info_rows = (const int*)d_in[5];
    const int*   info_cols = (const int*)d_in[6];
    const float* info_vals = (const float*)d_in[7];
    const int*   user_ids  = (const int*)d_in[8];
    const int*   item_ids  = (const int*)d_in[9];
    float*       out       = (float*)d_out;

    const int n_user = in_sizes[0] / 64;
    const int n_item = in_sizes[1] / 64;
    const int E_soc  = in_sizes[2];
    const int E_info = in_sizes[5];
    const int batch  = in_sizes[8];

    const int nbinS = (n_user + 255) >> PB;
    int capS = (int)((long long)E_soc * 256 / n_user);
    capS = capS + capS / 16 + 96;
    if (capS > CAPS) capS = CAPS;
    int capM = (int)((long long)E_info * 16 / n_user);
    capM = capM + capM / 4 + 64;
    if (capM > CAPM_LDS) capM = CAPM_LDS;

    // ---- workspace layout ----
    char* p = (char*)d_ws;
    auto alloc = [&](size_t bytes) { char* q = p; p += (bytes + 255) & ~size_t(255); return q; };
    int* mark     = (int*)alloc(sizeof(int) * n_user);
    int* n_marked = (int*)alloc(sizeof(int) * 64);
    size_t zero_bytes = (size_t)(p - (char*)d_ws);
    int*  mlist   = (int*)alloc(sizeof(int) * batch);
    int*  curSoc  = (int*)alloc(sizeof(int) * nbinS);
    int*  curMI   = (int*)alloc(sizeof(int) * NBINM_MAX);
    int2* bufSoc  = (int2*)alloc(sizeof(int2) * (size_t)nbinS * capS);       // ~27.5 MB
    int2* csrSoc  = (int2*)alloc(sizeof(int2) * (size_t)nbinS * capS);       // ~27.5 MB
    int2* rowptr2 = (int2*)alloc(sizeof(int2) * (size_t)n_user);             // 0.8 MB
    int2* bufMI   = (int2*)alloc(sizeof(int2) * (size_t)NBINM_MAX * capM);   // ~6 MB
    unsigned short* ub = (unsigned short*)alloc(sizeof(short) * (size_t)n_user * 64);
    unsigned short* ib = (unsigned short*)alloc(sizeof(short) * (size_t)n_item * 64);
    unsigned short* hb = (unsigned short*)alloc(sizeof(short) * (size_t)n_user * 64);
    float* accS        = (float*)alloc(sizeof(float) * (size_t)batch * 64);
    float* accI        = (float*)alloc(sizeof(float) * (size_t)batch * 64);
    (void)ws_size;

    hipMemsetAsync(d_ws, 0, zero_bytes, stream);

    const int B = 256;
    long long na = (long long)n_user * 64, nbm = (long long)n_item * 64;
    long long c4 = (na > nbm ? na : nbm) / 4;
    conv_kernel<<<(int)((c4 + B - 1) / B), B, 0, stream>>>(user_emb, ub, na, item_emb, ib, nbm);

    mark_init_kernel<<<(batch + B - 1) / B, B, 0, stream>>>(user_ids, mark, mlist, n_marked,
                                                            batch, curSoc, nbinS, capS,
                                                            curMI, capM);

    int gA = (E_soc + CHUNK_A - 1) / CHUNK_A;
    partA_soc<<<gA, 512, 0, stream>>>(soc_rows, soc_cols, soc_vals, curSoc, bufSoc,
                                      E_soc, nbinS, capS);

    int gAi = (E_info + CHUNK_A - 1) / CHUNK_A;
    partA_info<<<gAi, 512, 0, stream>>>(info_rows, info_cols, info_vals, E_info,
                                        mark, curMI, bufMI, capM);

    partB_sort<<<nbinS, 512, 0, stream>>>(curSoc, bufSoc, csrSoc, rowptr2, n_user, capS);

    long long t1 = (long long)n_user * 64;
    gather1_kernel<<<(int)((t1 + B - 1) / B), B, 0, stream>>>(rowptr2, csrSoc, ub, hb, n_user);

    long long t2 = (long long)batch * 64;
    accS_kernel<<<(int)((t2 + B - 1) / B), B, 0, stream>>>(mlist, n_marked, rowptr2, csrSoc,
                                                           hb, accS);

    int gBi = (batch + 15) >> PBM;
    partB_accI<<<gBi, B, 0, stream>>>(n_marked, curMI, bufMI, ib, accI, capM);

    dot_kernel<<<(int)((t2 + B - 1) / B), B, 0, stream>>>(hb, accS, accI, ib, mark,
                                                          user_ids, item_ids, out, batch);
}

// Round 11
// 207.049 us; speedup vs baseline: 1.4507x; 1.3376x over previous
//
#include <hip/hip_runtime.h>
#include <hip/hip_bf16.h>

#define CHUNK_A 4096      // edges per partition block (8 per thread, 512 threads)
#define PB 8              // 256 users per soc bin
#define NBINS_MAX 512     // LDS bound for soc bins (n_user/256 = 391)
#define CAPS 8800         // soc bin capacity (mean 8192 + ~6.7 sigma)
#define PBM 4             // 16 marked users per bin
#define NBINM_MAX 1024    // marked bins (batch/16)
#define CAPM_LDS 768      // marked-info bin capacity (mean 512 + ~11 sigma)

__device__ __forceinline__ float bf2f(unsigned short u) {
    return __uint_as_float(((unsigned int)u) << 16);
}
__device__ __forceinline__ unsigned short f2bf(float f) {
    unsigned int x = __float_as_uint(f);
    return (unsigned short)((x + 0x7fffu + ((x >> 16) & 1u)) >> 16);  // RNE
}
__device__ __forceinline__ void unpk(unsigned int u, float& lo, float& hi) {
    lo = __uint_as_float(u << 16);
    hi = __uint_as_float(u & 0xffff0000u);
}
__device__ __forceinline__ unsigned int pack2(float lo, float hi) {
    return (unsigned int)f2bf(lo) | ((unsigned int)f2bf(hi) << 16);
}

// ---------------- kernels ----------------

// Fused: f32->bf16 conversion (ub, ib) + dedup-mark users + init bin cursors.
__global__ __launch_bounds__(256) void conv_mark_kernel(const float* __restrict__ a,
                                                        unsigned short* __restrict__ oa, long long na,
                                                        const float* __restrict__ b,
                                                        unsigned short* __restrict__ ob, long long nb,
                                                        const int* __restrict__ ids,
                                                        int* __restrict__ mark,
                                                        int* __restrict__ mlist,
                                                        int* __restrict__ n_marked, int n,
                                                        int* __restrict__ curS, int nbinS, int capS,
                                                        int* __restrict__ curMI, int capM) {
    long long t = (long long)blockIdx.x * blockDim.x + threadIdx.x;
    long long i4 = t * 4;
    if (i4 < na) {
        float4 f = *(const float4*)&a[i4];
        ushort4 o = { f2bf(f.x), f2bf(f.y), f2bf(f.z), f2bf(f.w) };
        *(ushort4*)&oa[i4] = o;
    }
    if (i4 < nb) {
        float4 f = *(const float4*)&b[i4];
        ushort4 o = { f2bf(f.x), f2bf(f.y), f2bf(f.z), f2bf(f.w) };
        *(ushort4*)&ob[i4] = o;
    }
    int i = (int)t;
    if (i < nbinS) curS[i] = i * capS;
    if (i < NBINM_MAX) curMI[i] = i * capM;
    if (i < n) {
        int u = ids[i];
        if (atomicCAS(&mark[u], 0, -1) == 0) {
            int m = atomicAdd(n_marked, 1);
            mlist[m] = u;
            mark[u] = m + 1;
        }
    }
}

// Merged Phase A: partition soc edges into 256-user bins AND info edges (marked
// rows only) into 16-marked-user bins, in one pass. Edges register-cached
// (8/thread, vectorized loads) so each array is read exactly once.
__global__ __launch_bounds__(512) void partA_all(const int* __restrict__ sr,
                                                 const int* __restrict__ sc,
                                                 const float* __restrict__ sv, int Es,
                                                 const int* __restrict__ ir,
                                                 const int* __restrict__ ic,
                                                 const float* __restrict__ iv, int Ei,
                                                 const int* __restrict__ mark,
                                                 int* __restrict__ curS, int2* __restrict__ bufS,
                                                 int nbinS, int capS,
                                                 int* __restrict__ curMI, int2* __restrict__ bufMI,
                                                 int capM) {
    __shared__ int hS[NBINS_MAX], gS[NBINS_MAX], lS[NBINS_MAX];
    __shared__ int hI[NBINM_MAX], gI[NBINM_MAX], lI[NBINM_MAX];
    int tid = threadIdx.x;
    int base = blockIdx.x * CHUNK_A;
    for (int b = tid; b < nbinS; b += 512) hS[b] = 0;
    for (int b = tid; b < NBINM_MAX; b += 512) hI[b] = 0;

    // ---- register-cache 8 soc + 8 info edges per thread ----
    int e0 = base + tid * 8;
    int rS[8], cS[8], mI[8], cI[8];
    float vS[8], vI[8];
    int nS = (e0 < Es) ? min(8, Es - e0) : 0;
    int nI = (e0 < Ei) ? min(8, Ei - e0) : 0;
    if (nS == 8) {
        *(int4*)&rS[0] = *(const int4*)&sr[e0]; *(int4*)&rS[4] = *(const int4*)&sr[e0 + 4];
        *(int4*)&cS[0] = *(const int4*)&sc[e0]; *(int4*)&cS[4] = *(const int4*)&sc[e0 + 4];
        *(float4*)&vS[0] = *(const float4*)&sv[e0]; *(float4*)&vS[4] = *(const float4*)&sv[e0 + 4];
    } else {
        #pragma unroll 8
        for (int k = 0; k < 8; ++k)
            if (k < nS) { rS[k] = sr[e0 + k]; cS[k] = sc[e0 + k]; vS[k] = sv[e0 + k]; }
    }
    int rI[8];
    if (nI == 8) {
        *(int4*)&rI[0] = *(const int4*)&ir[e0]; *(int4*)&rI[4] = *(const int4*)&ir[e0 + 4];
        *(int4*)&cI[0] = *(const int4*)&ic[e0]; *(int4*)&cI[4] = *(const int4*)&ic[e0 + 4];
        *(float4*)&vI[0] = *(const float4*)&iv[e0]; *(float4*)&vI[4] = *(const float4*)&iv[e0 + 4];
    } else {
        #pragma unroll 8
        for (int k = 0; k < 8; ++k)
            if (k < nI) { rI[k] = ir[e0 + k]; cI[k] = ic[e0 + k]; vI[k] = iv[e0 + k]; }
    }
    #pragma unroll 8
    for (int k = 0; k < 8; ++k) mI[k] = (k < nI) ? mark[rI[k]] : 0;
    __syncthreads();

    // ---- LDS histograms ----
    #pragma unroll 8
    for (int k = 0; k < 8; ++k) if (k < nS) atomicAdd(&hS[rS[k] >> PB], 1);
    #pragma unroll 8
    for (int k = 0; k < 8; ++k) if (mI[k] > 0) atomicAdd(&hI[(mI[k] - 1) >> PBM], 1);
    __syncthreads();

    // ---- reserve global ranges (one hot atomic per non-empty (block,bin)) ----
    for (int b = tid; b < nbinS; b += 512) {
        int h = hS[b]; gS[b] = h ? atomicAdd(&curS[b], h) : 0; lS[b] = 0;
    }
    for (int b = tid; b < NBINM_MAX; b += 512) {
        int h = hI[b]; gI[b] = h ? atomicAdd(&curMI[b], h) : 0; lI[b] = 0;
    }
    __syncthreads();

    // ---- scatter from registers ----
    #pragma unroll 8
    for (int k = 0; k < 8; ++k) {
        if (k < nS) {
            int r = rS[k];
            int b = r >> PB;
            int off = atomicAdd(&lS[b], 1);
            long long dst = (long long)gS[b] + off;
            if (dst < (long long)(b + 1) * capS)
                bufS[dst] = make_int2(((r & 255) << 17) | cS[k], __float_as_int(vS[k]));
        }
    }
    #pragma unroll 8
    for (int k = 0; k < 8; ++k) {
        if (mI[k] > 0) {
            int m = mI[k] - 1;
            int b = m >> PBM;
            int off = atomicAdd(&lI[b], 1);
            long long dst = (long long)gI[b] + off;
            if (dst < (long long)(b + 1) * capM)
                bufMI[dst] = make_int2(((m & 15) << 17) | cI[k], __float_as_int(vI[k]));
        }
    }
}

// Phase B sort: per soc bin, LDS hist+scan of 256 local rows, then write the
// fully row-sorted CSR (col,val) + per-row [start,end) to rowptr2. Tiny LDS.
__global__ __launch_bounds__(512) void partB_sort(const int* __restrict__ curS,
                                                  const int2* __restrict__ bufS,
                                                  int2* __restrict__ csr,
                                                  int2* __restrict__ rowptr2,
                                                  int n_user, int capS) {
    int bin = blockIdx.x;
    int rows0 = bin << PB;
    int nrows = min(256, n_user - rows0);
    __shared__ int cur[256], wsum[4];
    int tid = threadIdx.x;
    if (tid < 256) cur[tid] = 0;
    __syncthreads();
    int gstart = bin * capS;
    int gend = curS[bin];
    if (gend > gstart + capS) gend = gstart + capS;
    int cnt = gend - gstart;
    for (int i = tid; i < cnt; i += 512) atomicAdd(&cur[bufS[gstart + i].x >> 17], 1);
    __syncthreads();
    int lane = tid & 63, wid = tid >> 6;
    int x = 0, v = 0;
    if (tid < 256) {
        x = cur[tid]; v = x;
        #pragma unroll
        for (int d = 1; d < 64; d <<= 1) { int y = __shfl_up(v, d); if (lane >= d) v += y; }
        if (lane == 63) wsum[wid] = v;
    }
    __syncthreads();
    if (tid == 0) {
        int s = 0;
        #pragma unroll
        for (int k = 0; k < 4; ++k) { int t = wsum[k]; wsum[k] = s; s += t; }
    }
    __syncthreads();
    if (tid < 256) {
        int excl = wsum[wid] + v - x;
        if (tid < nrows) rowptr2[rows0 + tid] = make_int2(gstart + excl, gstart + excl + x);
        cur[tid] = excl;
    }
    __syncthreads();
    for (int i = tid; i < cnt; i += 512) {
        int2 e = bufS[gstart + i];
        int rl = e.x >> 17;
        int p = atomicAdd(&cur[rl], 1);
        csr[gstart + p] = make_int2(e.x & 0x1FFFF, e.y);
    }
}

// gather1: one wave per user row; 8 edge slots x 8 lanes x ushort8 (int4) loads.
// h1[r] = (sum val*ub[col])/(sum val+eps) + ub[r], bf16 out.
__global__ __launch_bounds__(256) void gather1_kernel(const int2* __restrict__ rowptr2,
                                                      const int2* __restrict__ csr,
                                                      const unsigned short* __restrict__ ub,
                                                      unsigned short* __restrict__ hb,
                                                      int n_user) {
    int w = (int)((blockIdx.x * (long long)blockDim.x + threadIdx.x) >> 6);
    if (w >= n_user) return;
    int lane = threadIdx.x & 63;
    int sub = lane >> 3;
    int d8 = (lane & 7) << 3;
    int2 seg = rowptr2[w];
    float a0 = 0, a1 = 0, a2 = 0, a3 = 0, a4 = 0, a5 = 0, a6 = 0, a7 = 0, degs = 0;
    for (int j = seg.x + sub; j < seg.y; j += 8) {
        int2 e = csr[j];
        float vv = __int_as_float(e.y);
        int4 q = *(const int4*)&ub[(long long)e.x * 64 + d8];
        float f0, f1, f2, f3, f4, f5, f6, f7;
        unpk(q.x, f0, f1); unpk(q.y, f2, f3); unpk(q.z, f4, f5); unpk(q.w, f6, f7);
        a0 += vv * f0; a1 += vv * f1; a2 += vv * f2; a3 += vv * f3;
        a4 += vv * f4; a5 += vv * f5; a6 += vv * f6; a7 += vv * f7;
        degs += vv;
    }
    #pragma unroll
    for (int m = 8; m < 64; m <<= 1) {
        a0 += __shfl_xor(a0, m); a1 += __shfl_xor(a1, m);
        a2 += __shfl_xor(a2, m); a3 += __shfl_xor(a3, m);
        a4 += __shfl_xor(a4, m); a5 += __shfl_xor(a5, m);
        a6 += __shfl_xor(a6, m); a7 += __shfl_xor(a7, m);
        degs += __shfl_xor(degs, m);
    }
    if (sub == 0) {
        float inv = 1.0f / (degs + 1e-8f);
        int4 qe = *(const int4*)&ub[(long long)w * 64 + d8];
        float g0, g1, g2, g3, g4, g5, g6, g7;
        unpk(qe.x, g0, g1); unpk(qe.y, g2, g3); unpk(qe.z, g4, g5); unpk(qe.w, g6, g7);
        int4 o;
        o.x = (int)pack2(fmaf(a0, inv, g0), fmaf(a1, inv, g1));
        o.y = (int)pack2(fmaf(a2, inv, g2), fmaf(a3, inv, g3));
        o.z = (int)pack2(fmaf(a4, inv, g4), fmaf(a5, inv, g5));
        o.w = (int)pack2(fmaf(a6, inv, g6), fmaf(a7, inv, g7));
        *(int4*)&hb[(long long)w * 64 + d8] = o;
    }
}

// accS: one wave per marked row; gather h1 rows via the soc CSR.
// accS[m] = (sum val*hb[col])/(sum val+eps), f32 compact.
__global__ __launch_bounds__(256) void accS_kernel(const int* __restrict__ mlist,
                                                   const int* __restrict__ n_marked,
                                                   const int2* __restrict__ rowptr2,
                                                   const int2* __restrict__ csr,
                                                   const unsigned short* __restrict__ hb,
                                                   float* __restrict__ accS) {
    int w = (int)((blockIdx.x * (long long)blockDim.x + threadIdx.x) >> 6);
    if (w >= *n_marked) return;
    int lane = threadIdx.x & 63;
    int sub = lane >> 3;
    int d8 = (lane & 7) << 3;
    int r = mlist[w];
    int2 seg = rowptr2[r];
    float a0 = 0, a1 = 0, a2 = 0, a3 = 0, a4 = 0, a5 = 0, a6 = 0, a7 = 0, degs = 0;
    for (int j = seg.x + sub; j < seg.y; j += 8) {
        int2 e = csr[j];
        float vv = __int_as_float(e.y);
        int4 q = *(const int4*)&hb[(long long)e.x * 64 + d8];
        float f0, f1, f2, f3, f4, f5, f6, f7;
        unpk(q.x, f0, f1); unpk(q.y, f2, f3); unpk(q.z, f4, f5); unpk(q.w, f6, f7);
        a0 += vv * f0; a1 += vv * f1; a2 += vv * f2; a3 += vv * f3;
        a4 += vv * f4; a5 += vv * f5; a6 += vv * f6; a7 += vv * f7;
        degs += vv;
    }
    #pragma unroll
    for (int m = 8; m < 64; m <<= 1) {
        a0 += __shfl_xor(a0, m); a1 += __shfl_xor(a1, m);
        a2 += __shfl_xor(a2, m); a3 += __shfl_xor(a3, m);
        a4 += __shfl_xor(a4, m); a5 += __shfl_xor(a5, m);
        a6 += __shfl_xor(a6, m); a7 += __shfl_xor(a7, m);
        degs += __shfl_xor(degs, m);
    }
    if (sub == 0) {
        float inv = 1.0f / (degs + 1e-8f);
        long long base = (long long)w * 64 + d8;
        float4 o0 = { a0 * inv, a1 * inv, a2 * inv, a3 * inv };
        float4 o1 = { a4 * inv, a5 * inv, a6 * inv, a7 * inv };
        *(float4*)&accS[base] = o0;
        *(float4*)&accS[base + 4] = o1;
    }
}

// accI: per 16-marked-user bin, LDS sort bufMI, gather item_emb.
// accI[m] = (sum val*ib[col])/(sum val+eps), f32 compact.
__global__ __launch_bounds__(256) void partB_accI(const int* __restrict__ n_marked,
                                                  const int* __restrict__ curMI,
                                                  const int2* __restrict__ bufMI,
                                                  const unsigned short* __restrict__ ib,
                                                  float* __restrict__ accI, int capM) {
    int bin = blockIdx.x;
    int nm = *n_marked;
    int rows0 = bin << PBM;
    if (rows0 >= nm) return;
    int nrows = min(16, nm - rows0);
    __shared__ int2 sI[CAPM_LDS];
    __shared__ int j0[17], cI[16];
    int tid = threadIdx.x;
    if (tid < 16) cI[tid] = 0;
    __syncthreads();
    long long gs = (long long)bin * capM;
    long long ge = curMI[bin];
    if (ge > gs + capM) ge = gs + capM;
    int cnt = (int)(ge - gs);
    for (int i = tid; i < cnt; i += 256) atomicAdd(&cI[bufMI[gs + i].x >> 17], 1);
    __syncthreads();
    int lane = tid & 63, wid = tid >> 6;
    if (wid == 0 && lane < 16) {
        int x = cI[lane], v = x;
        #pragma unroll
        for (int d = 1; d < 16; d <<= 1) { int y = __shfl_up(v, d); if (lane >= d) v += y; }
        j0[lane] = v - x; cI[lane] = v - x;
        if (lane == 15) j0[16] = v;
    }
    __syncthreads();
    for (int i = tid; i < cnt; i += 256) {
        int2 e = bufMI[gs + i];
        int p = atomicAdd(&cI[e.x >> 17], 1);
        sI[p] = make_int2(e.x & 0x1FFFF, e.y);
    }
    __syncthreads();
    int sub = lane >> 4, d4 = (lane & 15) << 2;
    for (int r = wid; r < nrows; r += 4) {
        int a = j0[r], b2 = j0[r + 1];
        float4 acc = make_float4(0.f, 0.f, 0.f, 0.f);
        float degs = 0.f;
        for (int j = a + sub; j < b2; j += 4) {
            int2 e = sI[j];
            float vv = __int_as_float(e.y);
            ushort4 q = *(const ushort4*)&ib[(long long)e.x * 64 + d4];
            acc.x += vv * bf2f(q.x); acc.y += vv * bf2f(q.y);
            acc.z += vv * bf2f(q.z); acc.w += vv * bf2f(q.w);
            degs += vv;
        }
        #pragma unroll
        for (int m = 16; m < 64; m <<= 1) {
            acc.x += __shfl_xor(acc.x, m); acc.y += __shfl_xor(acc.y, m);
            acc.z += __shfl_xor(acc.z, m); acc.w += __shfl_xor(acc.w, m);
            degs  += __shfl_xor(degs, m);
        }
        if (sub == 0) {
            float inv = 1.0f / (degs + 1e-8f);
            float4 o = make_float4(acc.x * inv, acc.y * inv, acc.z * inv, acc.w * inv);
            *(float4*)&accI[(long long)(rows0 + r) * 64 + d4] = o;
        }
    }
}

// out[i] = sigmoid( dot(2*h1[uid] + accS[m] + accI[m], 2*item_emb[iid]) )
__global__ __launch_bounds__(256) void dot_kernel(const unsigned short* __restrict__ hb,
                                                  const float* __restrict__ accS,
                                                  const float* __restrict__ accI,
                                                  const unsigned short* __restrict__ ib,
                                                  const int* __restrict__ mark,
                                                  const int* __restrict__ uids,
                                                  const int* __restrict__ iids,
                                                  float* __restrict__ out, int batch) {
    int w = (int)((blockIdx.x * (long long)blockDim.x + threadIdx.x) >> 6);
    int lane = threadIdx.x & 63;
    if (w >= batch) return;
    int u = uids[w], it = iids[w];
    long long m = (long long)(mark[u] - 1);
    float uv = 2.0f * bf2f(hb[(long long)u * 64 + lane]) + accS[m * 64 + lane] + accI[m * 64 + lane];
    float vv = 2.0f * bf2f(ib[(long long)it * 64 + lane]);
    float p = uv * vv;
    #pragma unroll
    for (int off = 32; off; off >>= 1) p += __shfl_xor(p, off);
    if (lane == 0) out[w] = 1.0f / (1.0f + __expf(-p));
}

// ---------------- launch ----------------

extern "C" void kernel_launch(void* const* d_in, const int* in_sizes, int n_in,
                              void* d_out, int out_size, void* d_ws, size_t ws_size,
                              hipStream_t stream) {
    const float* user_emb  = (const float*)d_in[0];
    const float* item_emb  = (const float*)d_in[1];
    const int*   soc_rows  = (const int*)d_in[2];
    const int*   soc_cols  = (const int*)d_in[3];
    const float* soc_vals  = (const float*)d_in[4];
    const int*   info_rows = (const int*)d_in[5];
    const int*   info_cols = (const int*)d_in[6];
    const float* info_vals = (const float*)d_in[7];
    const int*   user_ids  = (const int*)d_in[8];
    const int*   item_ids  = (const int*)d_in[9];
    float*       out       = (float*)d_out;

    const int n_user = in_sizes[0] / 64;
    const int n_item = in_sizes[1] / 64;
    const int E_soc  = in_sizes[2];
    const int E_info = in_sizes[5];
    const int batch  = in_sizes[8];

    const int nbinS = (n_user + 255) >> PB;
    int capS = (int)((long long)E_soc * 256 / n_user);
    capS = capS + capS / 16 + 96;
    if (capS > CAPS) capS = CAPS;
    int capM = (int)((long long)E_info * 16 / n_user);
    capM = capM + capM / 4 + 64;
    if (capM > CAPM_LDS) capM = CAPM_LDS;

    // ---- workspace layout ----
    char* p = (char*)d_ws;
    auto alloc = [&](size_t bytes) { char* q = p; p += (bytes + 255) & ~size_t(255); return q; };
    int* mark     = (int*)alloc(sizeof(int) * n_user);
    int* n_marked = (int*)alloc(sizeof(int) * 64);
    size_t zero_bytes = (size_t)(p - (char*)d_ws);
    int*  mlist   = (int*)alloc(sizeof(int) * batch);
    int*  curSoc  = (int*)alloc(sizeof(int) * nbinS);
    int*  curMI   = (int*)alloc(sizeof(int) * NBINM_MAX);
    int2* bufSoc  = (int2*)alloc(sizeof(int2) * (size_t)nbinS * capS);       // ~27.5 MB
    int2* csrSoc  = (int2*)alloc(sizeof(int2) * (size_t)nbinS * capS);       // ~27.5 MB
    int2* rowptr2 = (int2*)alloc(sizeof(int2) * (size_t)n_user);             // 0.8 MB
    int2* bufMI   = (int2*)alloc(sizeof(int2) * (size_t)NBINM_MAX * capM);   // ~6 MB
    unsigned short* ub = (unsigned short*)alloc(sizeof(short) * (size_t)n_user * 64);
    unsigned short* ib = (unsigned short*)alloc(sizeof(short) * (size_t)n_item * 64);
    unsigned short* hb = (unsigned short*)alloc(sizeof(short) * (size_t)n_user * 64);
    float* accS        = (float*)alloc(sizeof(float) * (size_t)batch * 64);
    float* accI        = (float*)alloc(sizeof(float) * (size_t)batch * 64);
    (void)ws_size;

    hipMemsetAsync(d_ws, 0, zero_bytes, stream);

    const int B = 256;
    long long na = (long long)n_user * 64, nbm = (long long)n_item * 64;
    long long c4 = (na > nbm ? na : nbm) / 4;
    conv_mark_kernel<<<(int)((c4 + B - 1) / B), B, 0, stream>>>(
        user_emb, ub, na, item_emb, ib, nbm,
        user_ids, mark, mlist, n_marked, batch,
        curSoc, nbinS, capS, curMI, capM);

    int Emax = max(E_soc, E_info);
    int gA = (Emax + CHUNK_A - 1) / CHUNK_A;
    partA_all<<<gA, 512, 0, stream>>>(soc_rows, soc_cols, soc_vals, E_soc,
                                      info_rows, info_cols, info_vals, E_info,
                                      mark, curSoc, bufSoc, nbinS, capS,
                                      curMI, bufMI, capM);

    partB_sort<<<nbinS, 512, 0, stream>>>(curSoc, bufSoc, csrSoc, rowptr2, n_user, capS);

    long long t1 = (long long)n_user * 64;
    gather1_kernel<<<(int)((t1 + B - 1) / B), B, 0, stream>>>(rowptr2, csrSoc, ub, hb, n_user);

    long long t2 = (long long)batch * 64;
    accS_kernel<<<(int)((t2 + B - 1) / B), B, 0, stream>>>(mlist, n_marked, rowptr2, csrSoc,
                                                           hb, accS);

    int gBi = (batch + 15) >> PBM;
    partB_accI<<<gBi, B, 0, stream>>>(n_marked, curMI, bufMI, ib, accI, capM);

    dot_kernel<<<(int)((t2 + B - 1) / B), B, 0, stream>>>(hb, accS, accI, ib, mark,
                                                          user_ids, item_ids, out, batch);
}